// Round 5
// baseline (264.028 us; speedup 1.0000x reference)
//
#include <hip/hip_runtime.h>

// GASF: gasf[b,i,s1,s2,f] = cos(acos(a[s1,f]) + acos(a[s2,f]))
//                         = a1*a2 - sqrt(1-a1^2)*sqrt(1-a2^2)
// where a = clip(x / (2*std_ddof1), -1+eps, 1-eps). No trig needed
// (sin(acos(a)) = sqrt(1-a^2) exactly, since acos range is [0,pi]).
//
// B=64, I=8, S=128, F=8. Output 64*8*128*128*8 fp32 = 268 MB -> write-BW bound.
// Roofline: 268 MB / ~6.4 TB/s ~= 42 us.
//
// Layout: block = (pair, chunk-of-32-s1-rows). Thread t owns s2 = t>>1 and
// feat-half = t&1, so a wave's float4 store covers a CONTIGUOUS 1 KB
// (lane i -> row-offset i*16 B); 4 waves = one full 4 KB output row.

constexpr int SEQ  = 128;
constexpr int FEAT = 8;
constexpr int BI   = 64 * 8;                  // (b, imf) pairs
constexpr int CHUNKS = 4;                     // s1 chunks per pair
constexpr int ROWS = SEQ / CHUNKS;            // 32 rows per block

// Native clang vector type: __builtin_nontemporal_store rejects HIP's
// struct-based float4, but accepts ext_vector_type.
typedef float v4f __attribute__((ext_vector_type(4)));

__global__ __launch_bounds__(256) void gasf_kernel(const float* __restrict__ x,
                                                   float* __restrict__ out) {
    __shared__ float a_s[SEQ * FEAT];   // x staged, then a (in place)
    __shared__ float c_s[SEQ * FEAT];   // sqrt(1 - a^2)
    __shared__ float inv_s[FEAT];       // 1/(2*std) or 1.0 if std==0

    const int tid   = threadIdx.x;
    const int pair  = blockIdx.x >> 2;  // b*8 + i
    const int chunk = blockIdx.x & 3;

    const float* xp = x + (size_t)pair * (SEQ * FEAT);

    // ---- stage x[pair] (4 KB) into LDS, coalesced float4 ----
    reinterpret_cast<v4f*>(a_s)[tid] = reinterpret_cast<const v4f*>(xp)[tid];
    __syncthreads();

    // ---- wave 0: per-feature std (ddof=1) via 8-lane groups ----
    if (tid < 64) {
        const int f   = tid >> 3;
        const int sub = tid & 7;
        float sum = 0.0f, sq = 0.0f;
#pragma unroll
        for (int k = 0; k < 16; ++k) {
            float v = a_s[(sub + 8 * k) * FEAT + f];
            sum += v;
            sq = fmaf(v, v, sq);
        }
#pragma unroll
        for (int d = 1; d < 8; d <<= 1) {
            sum += __shfl_xor(sum, d);
            sq  += __shfl_xor(sq, d);
        }
        const float mean = sum * (1.0f / SEQ);
        const float var  = fmaxf((sq - sum * mean) * (1.0f / (SEQ - 1)), 0.0f);
        const float sd   = sqrtf(var);
        inv_s[f] = (sd > 0.0f) ? (1.0f / (2.0f * sd)) : 1.0f;  // where(std>0,...)
    }
    __syncthreads();

    // ---- per-element: a = clip(x*inv), c = sqrt(1 - a^2) ----
    {
        v4f v = reinterpret_cast<const v4f*>(a_s)[tid];
        const int f0 = (tid * 4) & 7;       // 0 or 4
        const float lo = -1.0f + 1e-8f;     // == -1.0f in fp32 (matches jnp clip)
        const float hi =  1.0f - 1e-8f;     // ==  1.0f in fp32
        v4f a, c;
#pragma unroll
        for (int j = 0; j < 4; ++j) {
            float s = v[j] * inv_s[f0 + j];
            s = fminf(fmaxf(s, lo), hi);
            a[j] = s;
            c[j] = sqrtf(fmaxf(fmaf(-s, s, 1.0f), 0.0f));
        }
        reinterpret_cast<v4f*>(a_s)[tid] = a;
        reinterpret_cast<v4f*>(c_s)[tid] = c;
    }
    __syncthreads();

    // ---- outer product: thread t owns (s2 = t>>1, feat-half = t&1) ----
    const int col_off = tid * 4;            // float offset within a 1024-float row
    const v4f a2 = *reinterpret_cast<const v4f*>(a_s + col_off);
    const v4f c2 = *reinterpret_cast<const v4f*>(c_s + col_off);
    const int fh4 = (tid & 1) * 4;          // 0 or 4: which feat-half of row s1

    const int s1_0 = chunk * ROWS;
    float* rowp = out + (size_t)pair * (SEQ * SEQ * FEAT)
                      + (size_t)s1_0 * (SEQ * FEAT) + col_off;

#pragma unroll
    for (int k = 0; k < ROWS; ++k) {
        const int s1 = s1_0 + k;
        // Two distinct LDS addrs per wave (fh alternates) -> 2-way broadcast, free.
        const v4f a1 = *reinterpret_cast<const v4f*>(a_s + s1 * FEAT + fh4);
        const v4f c1 = *reinterpret_cast<const v4f*>(c_s + s1 * FEAT + fh4);

        v4f o;
        o.x = fmaf(a1.x, a2.x, -(c1.x * c2.x));
        o.y = fmaf(a1.y, a2.y, -(c1.y * c2.y));
        o.z = fmaf(a1.z, a2.z, -(c1.z * c2.z));
        o.w = fmaf(a1.w, a2.w, -(c1.w * c2.w));

        // Dense wave store: lane i writes row-offset i*16 B -> contiguous 1 KB.
        __builtin_nontemporal_store(o, reinterpret_cast<v4f*>(rowp));
        rowp += SEQ * FEAT;
    }
}

extern "C" void kernel_launch(void* const* d_in, const int* in_sizes, int n_in,
                              void* d_out, int out_size, void* d_ws, size_t ws_size,
                              hipStream_t stream) {
    const float* x = (const float*)d_in[0];
    float* out = (float*)d_out;
    gasf_kernel<<<dim3(BI * CHUNKS), dim3(256), 0, stream>>>(x, out);
}